// Round 10
// baseline (143.616 us; speedup 1.0000x reference)
//
#include <hip/hip_runtime.h>
#include <stdint.h>

// ProtoNet loss pipeline on MI355X (gfx950) — round 10.
// C=256, S=5, Q=64, D_IN=1024, Z=128.
//
// Round-10: k_gemm_z = round-9 double-buffered async global_load_lds, but
// 32-row blocks for 2 blocks/CU (R9's 260x64-row grid = 1 block/CU -> the
// per-tile barrier vmcnt drain had no co-resident block to hide behind).
//  - 520 blocks x 256 thr; block = 32 rows x 128 cols; wave w = rows
//    (w&1)*16..+16, col-half (w>>1)*64..+64; acc[4].
//  - BK=64, 2 x (A 8KB fp32 + B 16KB bf16) = 48 KB LDS -> grid-limited
//    2.03 blocks/CU; barrier drains overlap the sibling block's compute.
//  - B re-read doubles (L2-resident, ~4us aggregate) ; A read once.
// k_prep, k_d2red unchanged.

typedef __attribute__((ext_vector_type(8))) short s8v;
typedef __attribute__((ext_vector_type(4))) float f32x4;

__device__ __forceinline__ short f2bf(float f) {
  union { float f; unsigned u; } v; v.f = f;
  unsigned r = (v.u + 0x7fffu + ((v.u >> 16) & 1u)) >> 16;   // RNE
  return (short)r;
}

// Async 16B/lane global->LDS. LDS arg = WAVE-UNIFORM base; HW deposits lane
// l at base + l*16. Global arg is per-lane.
__device__ __forceinline__ void async16(const void* g, void* s) {
  typedef __attribute__((address_space(3))) uint32_t lds_t;
  typedef const __attribute__((address_space(1))) uint32_t glb_t;
  __builtin_amdgcn_global_load_lds((glb_t*)(uintptr_t)g,
                                   (lds_t*)(uint32_t)(uintptr_t)s, 16, 0, 0);
}

// blocks 0..255: xbar[c,:] = mean_s xs[c,s,:] (+ block 0 zeroes out).
// blocks 256..271: Wt[n][k] = bf16(W[k][n]) via LDS transpose.
__global__ __launch_bounds__(256) void k_prep(
    const float* __restrict__ xs, const float* __restrict__ W,
    float* __restrict__ xbar, unsigned short* __restrict__ Wt,
    float* __restrict__ out) {
  __shared__ unsigned short T[128 * 68];
  const int tid = threadIdx.x;
  if (blockIdx.x < 256) {
    const int c = blockIdx.x;
    if (c == 0 && tid < 2) out[tid] = 0.0f;
    const float* b = xs + (size_t)c * 5120;
    for (int e = tid; e < 1024; e += 256) {
      float s = b[e] + b[1024 + e] + b[2048 + e] + b[3072 + e] + b[4096 + e];
      xbar[(size_t)c * 1024 + e] = s * 0.2f;
    }
  } else {
    const int kb = (blockIdx.x - 256) * 64;
#pragma unroll
    for (int s = 0; s < 8; ++s) {
      int idx = tid + s * 256;
      int kr = idx >> 5, n4 = idx & 31;
      float4 v = *(const float4*)(W + (size_t)(kb + kr) * 128 + n4 * 4);
      T[(n4 * 4 + 0) * 68 + kr] = (unsigned short)f2bf(v.x);
      T[(n4 * 4 + 1) * 68 + kr] = (unsigned short)f2bf(v.y);
      T[(n4 * 4 + 2) * 68 + kr] = (unsigned short)f2bf(v.z);
      T[(n4 * 4 + 3) * 68 + kr] = (unsigned short)f2bf(v.w);
    }
    __syncthreads();
#pragma unroll
    for (int s = 0; s < 8; ++s) {
      int idx = tid + s * 256;
      int n = idx >> 4, k4 = idx & 15;
      ushort4 o;
      o.x = T[n * 68 + k4 * 4 + 0];
      o.y = T[n * 68 + k4 * 4 + 1];
      o.z = T[n * 68 + k4 * 4 + 2];
      o.w = T[n * 68 + k4 * 4 + 3];
      *(ushort4*)(Wt + (size_t)n * 1024 + kb + k4 * 4) = o;
    }
  }
}

// ---------------- z = [xbar ; xq] @ W,  M=16640 N=128 K=1024 ----------------
// 520 blocks x 256 thr. Block = 32 rows x 128 cols; wave w: rows rg=(w&1),
// col-half ch=(w>>1). BK=64, 16 tiles, double-buffered async staging.
// Per buffer: A = 8 regions x 1KB fp32 (ar: r16g=ar>>2, ks=(ar>>1)&1, e=ar&1),
//             B = 16 regions x 1KB bf16 (br: t=br>>1, ks=br&1) at +8192.
// Region layout: lane l at base + l*16 (HW-forced) == frag read layout.
__global__ __launch_bounds__(256, 2) void k_gemm_z(
    const float* __restrict__ xbar, const float* __restrict__ xq,
    const unsigned short* __restrict__ Wt,
    unsigned short* __restrict__ zb, float* __restrict__ n2) {
  __shared__ __align__(16) char SM[2][24576];   // [buf][A 8KB | B 16KB]
  __shared__ float P[4][16];
  const int tid = threadIdx.x;
  const int w = tid >> 6, l = tid & 63, ln = l & 15, qd = l >> 4;
  const int rg = w & 1, ch = w >> 1;
  const int mb = blockIdx.x * 32;
  const float* abase = (mb < 256) ? (xbar + (size_t)mb * 1024)
                                  : (xq + (size_t)(mb - 256) * 1024);
  // staging sources: wave w stages A regions 2w..2w+1, B regions 4w..4w+3
  const float* as[2];
#pragma unroll
  for (int i = 0; i < 2; ++i) {
    int ar = w * 2 + i;
    int r16g = ar >> 2, ks = (ar >> 1) & 1, e = ar & 1;
    as[i] = abase + (size_t)(r16g * 16 + ln) * 1024 + ks * 32 + qd * 8 + e * 4;
  }
  const unsigned short* bs[4];
#pragma unroll
  for (int i = 0; i < 4; ++i) {
    int br = w * 4 + i;
    int t = br >> 1, ks = br & 1;
    bs[i] = Wt + (size_t)(t * 16 + ln) * 1024 + ks * 32 + qd * 8;
  }

  f32x4 acc[4] = {};

  // stage tile 0 -> buf 0
#pragma unroll
  for (int i = 0; i < 2; ++i)
    async16(as[i], SM[0] + (w * 2 + i) * 1024);
#pragma unroll
  for (int i = 0; i < 4; ++i)
    async16(bs[i], SM[0] + 8192 + (w * 4 + i) * 1024);

  for (int kt = 0; kt < 16; ++kt) {
    const int buf = kt & 1;
    __syncthreads();              // drains tile kt (issued last iter)
    if (kt < 15) {                // issue tile kt+1 -> other buffer
#pragma unroll
      for (int i = 0; i < 2; ++i)
        async16(as[i] + (kt + 1) * 64, SM[buf ^ 1] + (w * 2 + i) * 1024);
#pragma unroll
      for (int i = 0; i < 4; ++i)
        async16(bs[i] + (kt + 1) * 64, SM[buf ^ 1] + 8192 + (w * 4 + i) * 1024);
    }
    // compute tile kt from buf
#pragma unroll
    for (int ks = 0; ks < 2; ++ks) {
      f32x4 alo = *(const f32x4*)(SM[buf] + (rg * 4 + ks * 2 + 0) * 1024 + l * 16);
      f32x4 ahi = *(const f32x4*)(SM[buf] + (rg * 4 + ks * 2 + 1) * 1024 + l * 16);
      s8v af = { f2bf(alo[0]), f2bf(alo[1]), f2bf(alo[2]), f2bf(alo[3]),
                 f2bf(ahi[0]), f2bf(ahi[1]), f2bf(ahi[2]), f2bf(ahi[3]) };
#pragma unroll
      for (int t = 0; t < 4; ++t) {
        int br = (ch * 4 + t) * 2 + ks;
        s8v bf = *(const s8v*)(SM[buf] + 8192 + br * 1024 + l * 16);
        acc[t] = __builtin_amdgcn_mfma_f32_16x16x32_bf16(af, bf, acc[t], 0, 0, 0);
      }
    }
  }
  // epilogue: bf16 z + n2 (row partial over this wave's 64 cols, combine x2)
#pragma unroll
  for (int p = 0; p < 4; ++p) {
    const int grow = mb + rg * 16 + qd * 4 + p;   // C/D: row = quad*4 + reg
    float sp = 0.0f;
#pragma unroll
    for (int t = 0; t < 4; ++t) {
      float v = acc[t][p];                        // col = ch*64 + t*16 + ln
      zb[(size_t)grow * 128 + ch * 64 + t * 16 + ln] = (unsigned short)f2bf(v);
      sp += v * v;
    }
    sp += __shfl_xor(sp, 1);
    sp += __shfl_xor(sp, 2);
    sp += __shfl_xor(sp, 4);
    sp += __shfl_xor(sp, 8);
    if (ln == 0) P[w][qd * 4 + p] = sp;
  }
  __syncthreads();
  if (tid < 32) {                 // w = rg + 2*ch  ->  combine ch=0,1
    const int r = tid >> 4, i = tid & 15;
    n2[mb + r * 16 + i] = P[r][i] + P[r + 2][i];
  }
}

// --------- fused d2 GEMM (64 queries x 256 protos) + per-class reduce ---------
__global__ __launch_bounds__(256, 1) void k_d2red(
    const unsigned short* __restrict__ zb, const float* __restrict__ n2,
    float* __restrict__ out) {
  __shared__ float Dt[256 * 65];          // Dt[j][q], stride 65 (bank-free)
  __shared__ float rv[256];
  __shared__ int   ri[256];
  __shared__ float rss[256];
  __shared__ float invn[64];
  __shared__ float sred[4];
  __shared__ float s_tc, s_aq2, s_corr;
  const int tid = threadIdx.x;
  const int c = blockIdx.x;
  const int w = tid >> 6, lane = tid & 63, ln = lane & 15, qd = lane >> 4;

  f32x4 acc[16] = {};
  const unsigned short* Az = zb + (size_t)(256 + c * 64 + w * 16 + ln) * 128;
  s8v af[4];
#pragma unroll
  for (int kt = 0; kt < 4; ++kt) af[kt] = *(const s8v*)(Az + kt * 32 + qd * 8);
#pragma unroll
  for (int t = 0; t < 16; ++t) {
    const unsigned short* Bz = zb + (size_t)(t * 16 + ln) * 128 + qd * 8;
    s8v bf0 = *(const s8v*)(Bz + 0 * 32);
    s8v bf1 = *(const s8v*)(Bz + 1 * 32);
    s8v bf2 = *(const s8v*)(Bz + 2 * 32);
    s8v bf3 = *(const s8v*)(Bz + 3 * 32);
    acc[t] = __builtin_amdgcn_mfma_f32_16x16x32_bf16(af[0], bf0, acc[t], 0, 0, 0);
    acc[t] = __builtin_amdgcn_mfma_f32_16x16x32_bf16(af[1], bf1, acc[t], 0, 0, 0);
    acc[t] = __builtin_amdgcn_mfma_f32_16x16x32_bf16(af[2], bf2, acc[t], 0, 0, 0);
    acc[t] = __builtin_amdgcn_mfma_f32_16x16x32_bf16(af[3], bf3, acc[t], 0, 0, 0);
  }
#pragma unroll
  for (int p = 0; p < 4; ++p) {
    int qloc = w * 16 + qd * 4 + p;
    float qn = n2[256 + c * 64 + qloc];
#pragma unroll
    for (int t = 0; t < 16; ++t) {
      int j = t * 16 + ln;
      Dt[j * 65 + qloc] = qn + n2[j] - 2.0f * acc[t][p];
    }
  }
  __syncthreads();

  {
    const int q = tid & 63, jb = (tid >> 6) * 64;
    float mn = 3.4e38f; int mi = 0; float ss = 0.0f;
    for (int jj = 0; jj < 64; ++jj) {
      int j = jb + jj;
      float f = Dt[j * 65 + q];
      ss += f * f;
      if (f < mn) { mn = f; mi = j; }
    }
    rv[tid] = mn; ri[tid] = mi; rss[tid] = ss;
  }
  __syncthreads();
  if (tid < 64) {
    float bm = rv[tid]; int bi = ri[tid]; float ss = rss[tid];
    for (int hh = 1; hh < 4; ++hh) {
      float v = rv[hh * 64 + tid];
      ss += rss[hh * 64 + tid];
      if (v < bm) { bm = v; bi = ri[hh * 64 + tid]; }
    }
    float col = Dt[c * 65 + tid];
    float loo2 = fmaxf(ss - col * col, 0.0f);
    float nrm = fmaxf(sqrtf(loo2), 1e-8f);
    float inv = 1.0f / nrm;
    invn[tid] = inv;
    float aq2 = loo2 * inv * inv;
    float corr = (bi == c) ? 1.0f : 0.0f;
    for (int m = 1; m < 64; m <<= 1) {
      aq2 += __shfl_xor(aq2, m);
      corr += __shfl_xor(corr, m);
    }
    if (tid == 0) { s_aq2 = aq2; s_corr = corr; }
  }
  __syncthreads();
  float t = 0.0f;
  for (int qq = 0; qq < 64; ++qq) t += Dt[tid * 65 + qq] * invn[qq];
  if (tid == c) s_tc = t;
  float t2 = t * t;
  for (int m = 1; m < 64; m <<= 1) t2 += __shfl_xor(t2, m);
  if ((tid & 63) == 0) sred[tid >> 6] = t2;
  __syncthreads();
  if (tid == 0) {
    float S2 = sred[0] + sred[1] + sred[2] + sred[3];
    float bs = 0.5f * (S2 - s_tc * s_tc - s_aq2);
    atomicAdd(&out[0], bs * (1.0f / 516096.0f));
    atomicAdd(&out[1], s_corr * (1.0f / 16384.0f));
  }
}

extern "C" void kernel_launch(void* const* d_in, const int* in_sizes, int n_in,
                              void* d_out, int out_size, void* d_ws, size_t ws_size,
                              hipStream_t stream) {
  const float* xs = (const float*)d_in[0];   // 256*5*1024
  const float* xq = (const float*)d_in[1];   // 256*64*1024
  const float* W  = (const float*)d_in[2];   // 1024*128
  float* out = (float*)d_out;

  float* ws = (float*)d_ws;
  float* xbar = ws;                                    // 262144 fp32 (1 MB)
  unsigned short* Wt = (unsigned short*)(xbar + 262144);          // 128K bf16
  unsigned short* zb = Wt + 131072;                               // 16640*128 bf16
  float* n2 = (float*)(zb + (size_t)16640 * 128);                 // 16640 fp32

  k_prep<<<dim3(272), dim3(256), 0, stream>>>(xs, W, xbar, Wt, out);
  k_gemm_z<<<dim3(520), dim3(256), 0, stream>>>(xbar, xq, Wt, zb, n2);
  k_d2red<<<dim3(256), dim3(256), 0, stream>>>(zb, n2, out);
}

// Round 11
// 135.376 us; speedup vs baseline: 1.0609x; 1.0609x over previous
//
#include <hip/hip_runtime.h>
#include <stdint.h>

// ProtoNet loss pipeline on MI355X (gfx950) — round 11.
// C=256, S=5, Q=64, D_IN=1024, Z=128.
//
// Round-11:
//  - k_gemm_z: revert to round-9 exactly (best measured: 64-row blocks,
//    BK=64 double-buffered async global_load_lds staging). R10's 32-row
//    2-blocks/CU variant regressed (43us): halved compute-per-drain and
//    +50% staged B traffic beat the co-residency gain.
//  - k_d2red: kill the last MLP=1 load serialization (64 serialized
//    global b128 B-loads/wave ~ 400cyc each ≈ 10us). Stage ALL 256 proto
//    rows (64KB) + the block's 64 query rows (16KB) via async
//    global_load_lds into fragment-major regions (one drain), MFMA from
//    conflict-free ds_read_b128, then reuse the LDS (union) for the
//    Dt/reduction phase. Reduction logic unchanged.
//  - k_prep: xbar vectorized to float4.

typedef __attribute__((ext_vector_type(8))) short s8v;
typedef __attribute__((ext_vector_type(4))) float f32x4;

__device__ __forceinline__ short f2bf(float f) {
  union { float f; unsigned u; } v; v.f = f;
  unsigned r = (v.u + 0x7fffu + ((v.u >> 16) & 1u)) >> 16;   // RNE
  return (short)r;
}

// Async 16B/lane global->LDS. LDS arg = WAVE-UNIFORM base; HW deposits lane
// l at base + l*16. Global arg is per-lane.
__device__ __forceinline__ void async16(const void* g, void* s) {
  typedef __attribute__((address_space(3))) uint32_t lds_t;
  typedef const __attribute__((address_space(1))) uint32_t glb_t;
  __builtin_amdgcn_global_load_lds((glb_t*)(uintptr_t)g,
                                   (lds_t*)(uint32_t)(uintptr_t)s, 16, 0, 0);
}

// blocks 0..255: xbar[c,:] = mean_s xs[c,s,:] (+ block 0 zeroes out).
// blocks 256..271: Wt[n][k] = bf16(W[k][n]) via LDS transpose.
__global__ __launch_bounds__(256) void k_prep(
    const float* __restrict__ xs, const float* __restrict__ W,
    float* __restrict__ xbar, unsigned short* __restrict__ Wt,
    float* __restrict__ out) {
  __shared__ unsigned short T[128 * 68];
  const int tid = threadIdx.x;
  if (blockIdx.x < 256) {
    const int c = blockIdx.x;
    if (c == 0 && tid < 2) out[tid] = 0.0f;
    const float* b = xs + (size_t)c * 5120;
    const float4* b4 = (const float4*)b;
    float4 s0 = b4[tid];
    float4 s1 = b4[256 + tid];
    float4 s2 = b4[512 + tid];
    float4 s3 = b4[768 + tid];
    float4 s4 = b4[1024 + tid];
    float4 r;
    r.x = (s0.x + s1.x + s2.x + s3.x + s4.x) * 0.2f;
    r.y = (s0.y + s1.y + s2.y + s3.y + s4.y) * 0.2f;
    r.z = (s0.z + s1.z + s2.z + s3.z + s4.z) * 0.2f;
    r.w = (s0.w + s1.w + s2.w + s3.w + s4.w) * 0.2f;
    *(float4*)(xbar + (size_t)c * 1024 + tid * 4) = r;
  } else {
    const int kb = (blockIdx.x - 256) * 64;
#pragma unroll
    for (int s = 0; s < 8; ++s) {
      int idx = tid + s * 256;
      int kr = idx >> 5, n4 = idx & 31;
      float4 v = *(const float4*)(W + (size_t)(kb + kr) * 128 + n4 * 4);
      T[(n4 * 4 + 0) * 68 + kr] = (unsigned short)f2bf(v.x);
      T[(n4 * 4 + 1) * 68 + kr] = (unsigned short)f2bf(v.y);
      T[(n4 * 4 + 2) * 68 + kr] = (unsigned short)f2bf(v.z);
      T[(n4 * 4 + 3) * 68 + kr] = (unsigned short)f2bf(v.w);
    }
    __syncthreads();
#pragma unroll
    for (int s = 0; s < 8; ++s) {
      int idx = tid + s * 256;
      int n = idx >> 4, k4 = idx & 15;
      ushort4 o;
      o.x = T[n * 68 + k4 * 4 + 0];
      o.y = T[n * 68 + k4 * 4 + 1];
      o.z = T[n * 68 + k4 * 4 + 2];
      o.w = T[n * 68 + k4 * 4 + 3];
      *(ushort4*)(Wt + (size_t)n * 1024 + kb + k4 * 4) = o;
    }
  }
}

// ---------------- z = [xbar ; xq] @ W,  M=16640 N=128 K=1024 ----------------
// Round-9 structure (verbatim): 260 blocks x 256 thr; wave w = rows w*16..+15
// x all 128 cols; BK=64, 16 tiles, double-buffered async staging.
__global__ __launch_bounds__(256, 2) void k_gemm_z(
    const float* __restrict__ xbar, const float* __restrict__ xq,
    const unsigned short* __restrict__ Wt,
    unsigned short* __restrict__ zb, float* __restrict__ n2) {
  __shared__ __align__(16) char SM[2][32768];   // [buf][A 16KB | B 16KB]
  const int tid = threadIdx.x;
  const int w = tid >> 6, l = tid & 63, ln = l & 15, qd = l >> 4;
  const int mb = blockIdx.x * 64;
  const float* abase = (mb < 256) ? (xbar + (size_t)mb * 1024)
                                  : (xq + (size_t)(mb - 256) * 1024);
  const float* as[4];
#pragma unroll
  for (int i = 0; i < 4; ++i)     // e=i&1, ks=i>>1
    as[i] = abase + (size_t)(w * 16 + ln) * 1024 + (i >> 1) * 32 + qd * 8 + (i & 1) * 4;
  const unsigned short* bs[4];    // i: t=2w+(i>>1), ks=i&1
  bs[0] = Wt + (size_t)(2 * w * 16 + ln) * 1024 + qd * 8;
  bs[1] = bs[0] + 32;
  bs[2] = bs[0] + 16 * 1024;
  bs[3] = bs[2] + 32;

  f32x4 acc[8] = {};

  // stage tile 0 -> buf 0
#pragma unroll
  for (int i = 0; i < 4; ++i)
    async16(as[i], SM[0] + (w * 4 + i) * 1024);
#pragma unroll
  for (int i = 0; i < 4; ++i)
    async16(bs[i], SM[0] + 16384 + (w * 4 + i) * 1024);

  for (int kt = 0; kt < 16; ++kt) {
    const int buf = kt & 1;
    __syncthreads();              // drains tile kt (issued last iter)
    if (kt < 15) {                // issue tile kt+1 -> other buffer
#pragma unroll
      for (int i = 0; i < 4; ++i)
        async16(as[i] + (kt + 1) * 64, SM[buf ^ 1] + (w * 4 + i) * 1024);
#pragma unroll
      for (int i = 0; i < 4; ++i)
        async16(bs[i] + (kt + 1) * 64, SM[buf ^ 1] + 16384 + (w * 4 + i) * 1024);
    }
    // compute tile kt from buf
#pragma unroll
    for (int ks = 0; ks < 2; ++ks) {
      f32x4 alo = *(const f32x4*)(SM[buf] + (w * 4 + ks * 2 + 0) * 1024 + l * 16);
      f32x4 ahi = *(const f32x4*)(SM[buf] + (w * 4 + ks * 2 + 1) * 1024 + l * 16);
      s8v af = { f2bf(alo[0]), f2bf(alo[1]), f2bf(alo[2]), f2bf(alo[3]),
                 f2bf(ahi[0]), f2bf(ahi[1]), f2bf(ahi[2]), f2bf(ahi[3]) };
#pragma unroll
      for (int t = 0; t < 8; ++t) {
        s8v bf = *(const s8v*)(SM[buf] + 16384 + (t * 2 + ks) * 1024 + l * 16);
        acc[t] = __builtin_amdgcn_mfma_f32_16x16x32_bf16(af, bf, acc[t], 0, 0, 0);
      }
    }
  }
  // epilogue: bf16 z + full-row n2
#pragma unroll
  for (int p = 0; p < 4; ++p) {
    const int grow = mb + w * 16 + qd * 4 + p;   // C/D: row = quad*4 + reg
    float sp = 0.0f;
#pragma unroll
    for (int t = 0; t < 8; ++t) {
      float v = acc[t][p];                       // col = t*16 + ln
      zb[(size_t)grow * 128 + t * 16 + ln] = (unsigned short)f2bf(v);
      sp += v * v;
    }
    sp += __shfl_xor(sp, 1);
    sp += __shfl_xor(sp, 2);
    sp += __shfl_xor(sp, 4);
    sp += __shfl_xor(sp, 8);
    if (ln == 0) n2[grow] = sp;
  }
}

// --------- fused d2 GEMM (64 queries x 256 protos) + per-class reduce ---------
// Staging phase: protos (64 regions x 1KB) + queries (16 regions x 1KB) via
// async global_load_lds, one drain, MFMA from conflict-free ds_read_b128.
// Reduce phase reuses the same LDS (union) for Dt[256*65] + scratch.
__global__ __launch_bounds__(256, 1) void k_d2red(
    const unsigned short* __restrict__ zb, const float* __restrict__ n2,
    float* __restrict__ out) {
  __shared__ __align__(16) char SMu[83968];
  char* prot = SMu;                       // 64KB: region r=t*4+ks, lane at l*16
  char* az   = SMu + 65536;               // 16KB: region w*4+kt
  float* Dt  = (float*)SMu;               // 256*65 fp32 = 66560 B
  float* rv  = (float*)(SMu + 66560);     // 256 fp32
  int*   ri  = (int*)  (SMu + 67584);     // 256 int
  float* rss = (float*)(SMu + 68608);     // 256 fp32
  float* invn= (float*)(SMu + 69632);     // 64 fp32
  float* sred= (float*)(SMu + 69888);     // 4 fp32
  float* sc  = (float*)(SMu + 69904);     // [0]=tc [1]=aq2 [2]=corr
  const int tid = threadIdx.x;
  const int c = blockIdx.x;
  const int w = tid >> 6, l = tid & 63, ln = l & 15, qd = l >> 4;

  // ---- stage: queries (this block's 64 rows) + all 256 proto rows ----
#pragma unroll
  for (int i = 0; i < 4; ++i)
    async16(zb + (size_t)(256 + c * 64 + w * 16 + ln) * 128 + i * 32 + qd * 8,
            az + (w * 4 + i) * 1024);
#pragma unroll
  for (int i = 0; i < 16; ++i) {
    int r = w * 16 + i, t = r >> 2, ks = r & 3;
    async16(zb + (size_t)(t * 16 + ln) * 128 + ks * 32 + qd * 8,
            prot + r * 1024);
  }
  __syncthreads();                        // one drain for all 20 regions/wave

  // ---- MFMA: wave w = query rows w*16..+15 x all 256 protos ----
  f32x4 acc[16] = {};
  s8v af[4];
#pragma unroll
  for (int i = 0; i < 4; ++i)
    af[i] = *(const s8v*)(az + (w * 4 + i) * 1024 + l * 16);
#pragma unroll
  for (int t = 0; t < 16; ++t) {
#pragma unroll
    for (int ks = 0; ks < 4; ++ks) {
      s8v bf = *(const s8v*)(prot + (t * 4 + ks) * 1024 + l * 16);
      acc[t] = __builtin_amdgcn_mfma_f32_16x16x32_bf16(af[ks], bf, acc[t], 0, 0, 0);
    }
  }
  __syncthreads();                        // all LDS reads done before Dt writes

  // ---- Dt[j][q] = d2, stride 65 ----
#pragma unroll
  for (int p = 0; p < 4; ++p) {
    int qloc = w * 16 + qd * 4 + p;
    float qn = n2[256 + c * 64 + qloc];
#pragma unroll
    for (int t = 0; t < 16; ++t) {
      int j = t * 16 + ln;
      Dt[j * 65 + qloc] = qn + n2[j] - 2.0f * acc[t][p];
    }
  }
  __syncthreads();

  // per-row (query) stats: thread tid = row q=tid&63, j-quarter tid>>6
  {
    const int q = tid & 63, jb = (tid >> 6) * 64;
    float mn = 3.4e38f; int mi = 0; float ss = 0.0f;
    for (int jj = 0; jj < 64; ++jj) {
      int j = jb + jj;
      float f = Dt[j * 65 + q];
      ss += f * f;
      if (f < mn) { mn = f; mi = j; }
    }
    rv[tid] = mn; ri[tid] = mi; rss[tid] = ss;
  }
  __syncthreads();
  if (tid < 64) {   // combine quarters; ascending h + strict < => first-occurrence
    float bm = rv[tid]; int bi = ri[tid]; float ss = rss[tid];
    for (int hh = 1; hh < 4; ++hh) {
      float v = rv[hh * 64 + tid];
      ss += rss[hh * 64 + tid];
      if (v < bm) { bm = v; bi = ri[hh * 64 + tid]; }
    }
    float col = Dt[c * 65 + tid];
    float loo2 = fmaxf(ss - col * col, 0.0f);
    float nrm = fmaxf(sqrtf(loo2), 1e-8f);
    float inv = 1.0f / nrm;
    invn[tid] = inv;
    float aq2 = loo2 * inv * inv;          // ||a_q||^2
    float corr = (bi == c) ? 1.0f : 0.0f;
    for (int m = 1; m < 64; m <<= 1) {
      aq2 += __shfl_xor(aq2, m);
      corr += __shfl_xor(corr, m);
    }
    if (tid == 0) { sc[1] = aq2; sc[2] = corr; }
  }
  __syncthreads();
  // t[j] = sum_q D[q][j] * invn[q]; thread tid = j
  float t = 0.0f;
  for (int qq = 0; qq < 64; ++qq) t += Dt[tid * 65 + qq] * invn[qq];
  if (tid == c) sc[0] = t;
  float t2 = t * t;
  for (int m = 1; m < 64; m <<= 1) t2 += __shfl_xor(t2, m);
  if ((tid & 63) == 0) sred[tid >> 6] = t2;
  __syncthreads();
  if (tid == 0) {
    float S2 = sred[0] + sred[1] + sred[2] + sred[3];
    float bs = 0.5f * (S2 - sc[0] * sc[0] - sc[1]);  // sum_{q<k} sim
    atomicAdd(&out[0], bs * (1.0f / 516096.0f));     // / (C * Q*(Q-1)/2)
    atomicAdd(&out[1], sc[2] * (1.0f / 16384.0f));   // / (C*Q)
  }
}

extern "C" void kernel_launch(void* const* d_in, const int* in_sizes, int n_in,
                              void* d_out, int out_size, void* d_ws, size_t ws_size,
                              hipStream_t stream) {
  const float* xs = (const float*)d_in[0];   // 256*5*1024
  const float* xq = (const float*)d_in[1];   // 256*64*1024
  const float* W  = (const float*)d_in[2];   // 1024*128
  float* out = (float*)d_out;

  float* ws = (float*)d_ws;
  float* xbar = ws;                                    // 262144 fp32 (1 MB)
  unsigned short* Wt = (unsigned short*)(xbar + 262144);          // 128K bf16
  unsigned short* zb = Wt + 131072;                               // 16640*128 bf16
  float* n2 = (float*)(zb + (size_t)16640 * 128);                 // 16640 fp32

  k_prep<<<dim3(272), dim3(256), 0, stream>>>(xs, W, xbar, Wt, out);
  k_gemm_z<<<dim3(260), dim3(256), 0, stream>>>(xbar, xq, Wt, zb, n2);
  k_d2red<<<dim3(256), dim3(256), 0, stream>>>(zb, n2, out);
}